// Round 2
// baseline (18945.842 us; speedup 1.0000x reference)
//
#include <hip/hip_runtime.h>

#define Bv 128
#define Tv 256
#define Dv 512
#define Hv 1024
#define NG 4096   // 4*H

typedef __bf16 bf16x8 __attribute__((ext_vector_type(8)));
typedef float  f32x4  __attribute__((ext_vector_type(4)));
typedef unsigned short u16;

__device__ __forceinline__ u16 f2bf(float f){
  unsigned u = __float_as_uint(f);
  u = (u + 0x7FFFu + ((u >> 16) & 1u)) >> 16;
  return (u16)u;
}
__device__ __forceinline__ float bf2f(u16 b){ return __uint_as_float(((unsigned)b) << 16); }
__device__ __forceinline__ float fsig(float x){ return 1.0f / (1.0f + __expf(-x)); }
__device__ __forceinline__ float ftanh(float x){ return 1.0f - 2.0f / (1.0f + __expf(2.0f * x)); }

// ---------------- setup kernels ----------------

__global__ void cvt_f32_bf16(const float* __restrict__ src, u16* __restrict__ dst, int n4){
  int i = blockIdx.x * 256 + threadIdx.x;
  if (i < n4){
    float4 v = ((const float4*)src)[i];
    ushort4 o;
    o.x = f2bf(v.x); o.y = f2bf(v.y); o.z = f2bf(v.z); o.w = f2bf(v.w);
    ((ushort4*)dst)[i] = o;
  }
}

// Pack 4 gate matrices [K, 1024] fp32 into MFMA B-frag layout:
// out index o = ((ntile*KT + ktile)*64 + lane)*8 + j
// element = W[gate][k*1024 + col], k = ktile*32 + (lane>>4)*8 + j,
// n = ntile*16 + (lane&15), gate = n>>10, col = n&1023.
__global__ void pack_b(const float* __restrict__ Wi, const float* __restrict__ Wf,
                       const float* __restrict__ Wg, const float* __restrict__ Wo,
                       u16* __restrict__ dst, int KTm1, int ntshift){
  int o = blockIdx.x * 256 + threadIdx.x;
  int j = o & 7;
  int lane = (o >> 3) & 63;
  int kt = (o >> 9) & KTm1;
  int ntile = o >> ntshift;
  int k = kt * 32 + ((lane >> 4) << 3) + j;
  int n = ntile * 16 + (lane & 15);
  const float* src = (n < 1024) ? Wi : (n < 2048) ? Wf : (n < 3072) ? Wg : Wo;
  dst[o] = f2bf(src[k * 1024 + (n & 1023)]);
}

__global__ void pack_bias(const float* __restrict__ bi, const float* __restrict__ bfp,
                          const float* __restrict__ bg, const float* __restrict__ bo,
                          float* __restrict__ dst){
  int n = blockIdx.x * 256 + threadIdx.x;   // 0..4095
  const float* s = (n < 1024) ? bi : (n < 2048) ? bfp : (n < 3072) ? bg : bo;
  dst[n] = s[n & 1023];
}

// ---------------- pre-GEMM: Z = A @ Wpacked + bias ----------------
__global__ __launch_bounds__(256) void pregemm(const u16* __restrict__ A,
                                               const u16* __restrict__ Wp,
                                               const float* __restrict__ bias,
                                               u16* __restrict__ Z,
                                               int K){
  int w = threadIdx.x >> 6, lane = threadIdx.x & 63;
  int quad = lane >> 4, l15 = lane & 15;
  int nblk = blockIdx.x;   // 0..63
  int mblk = blockIdx.y;   // 0..255
  int KT = K >> 5;
  const u16* Arow0 = A + (size_t)(mblk * 128 + w * 32 + l15) * K;
  const u16* Arow1 = Arow0 + (size_t)16 * K;
  f32x4 acc[2][4] = {};
  for (int kt = 0; kt < KT; ++kt){
    int kofs = kt * 32 + quad * 8;
    bf16x8 a0 = *(const bf16x8*)(Arow0 + kofs);
    bf16x8 a1 = *(const bf16x8*)(Arow1 + kofs);
#pragma unroll
    for (int g = 0; g < 4; ++g){
      int ntile = nblk * 4 + g;
      bf16x8 b = *(const bf16x8*)(Wp + ((size_t)(ntile * KT + kt) * 64 + lane) * 8);
      acc[0][g] = __builtin_amdgcn_mfma_f32_16x16x32_bf16(a0, b, acc[0][g], 0, 0, 0);
      acc[1][g] = __builtin_amdgcn_mfma_f32_16x16x32_bf16(a1, b, acc[1][g], 0, 0, 0);
    }
  }
#pragma unroll
  for (int mt = 0; mt < 2; ++mt){
    int rowbase = mblk * 128 + w * 32 + mt * 16 + quad * 4;
#pragma unroll
    for (int g = 0; g < 4; ++g){
      int n = (nblk * 4 + g) * 16 + l15;
      float bv = bias[n];
#pragma unroll
      for (int r = 0; r < 4; ++r){
        Z[(size_t)(rowbase + r) * NG + n] = f2bf(acc[mt][g][r] + bv);
      }
    }
  }
}

// ---------------- persistent recurrent kernel ----------------
// One launch per layer; loops all T=256 timesteps internally.
// grid = (64 jt, 4 mq): block owns batch rows [mq*32, mq*32+32) x h-cols [jt*16, jt*16+16).
// 8 waves = (mtile m = w&1, gate g = w>>1). Each wave holds its U B-frags in
// 128 VGPRs (loaded once). c state lives in one VGPR per thread.
// Steps separated by a per-mq-group (64 block) device barrier on bar[mq*64];
// h ping-pongs between hA/hB so a one-step skew between groups is safe.
// Residency: <=256 VGPR -> 8 waves/CU -> exactly 1 block/CU -> all 256 blocks
// co-resident; barrier cannot deadlock by capacity. A bounded spin (sticky
// deadf) guarantees the kernel terminates even if that assumption breaks.
#define GP 68   // gst row pitch (floats), padded to break 4-way bank conflict

__global__ __launch_bounds__(512, 2) void lstm_persist(
    const u16* __restrict__ Up,
    const u16* __restrict__ Zbf,
    u16* hA, u16* hB,
    u16* __restrict__ dst_bf,
    float* __restrict__ out_h,
    float* __restrict__ out_c,
    unsigned* bar,
    int last)
{
  __shared__ float gst[32 * GP];   // gate pre-activations, 32 rows x 64 gate-cols
  int tid = threadIdx.x;
  int w = tid >> 6, lane = tid & 63;
  int quad = lane >> 4, l15 = lane & 15;
  int jt = blockIdx.x;      // 0..63  (h-col tile)
  int mq = blockIdx.y;      // 0..3   (batch group; barrier group)
  int m = w & 1, g = w >> 1;
  unsigned* barp = bar + mq * 64;   // 256B-padded counter per group

  // Load this wave's U fragments (gate g, ntile g*64+jt) into registers: 128 VGPRs.
  bf16x8 breg[32];
#pragma unroll
  for (int kt = 0; kt < 32; ++kt)
    breg[kt] = *(const bf16x8*)(Up + ((size_t)((g * 64 + jt) * 32 + kt) * 64 + lane) * 8);

  // Elementwise ownership: thread -> (row erow, h-col ecol), fixed for all t.
  int erow = tid >> 4;          // 0..31
  int ecol = tid & 15;          // 0..15
  int brow = mq * 32 + erow;    // global batch row
  int j = jt * 16 + ecol;       // global h col
  float creg = 0.0f;            // cell state (fp32), persistent in register

  const u16* hprev = hA;
  u16* hnext = hB;
  unsigned target = 0;
  int deadf = 0;                // sticky spin-timeout flag (leader only)
  const int arowidx = mq * 32 + m * 16 + l15;

  for (int t = 0; t < Tv; ++t){
    // Z prefetch for this step (consumed after the MFMA phase; latency hidden)
    const u16* zp = Zbf + ((size_t)brow * Tv + t) * NG + j;
    u16 z0 = zp[0], z1 = zp[Hv], z2 = zp[2 * Hv], z3 = zp[3 * Hv];

    // G_partial = hprev(mtile m) @ U(gate g, jt) -- same accumulation order as before
    const u16* arow = hprev + (size_t)arowidx * Hv + quad * 8;
    f32x4 acc = {};
#pragma unroll
    for (int kt = 0; kt < 32; ++kt){
      bf16x8 a = *(const bf16x8*)(arow + kt * 32);
      acc = __builtin_amdgcn_mfma_f32_16x16x32_bf16(a, breg[kt], acc, 0, 0, 0);
    }
#pragma unroll
    for (int r = 0; r < 4; ++r)
      gst[(m * 16 + quad * 4 + r) * GP + g * 16 + l15] = acc[r];
    __syncthreads();

    // gates + state update (identical math to previous kernel)
    float pi = gst[erow * GP +  0 + ecol] + bf2f(z0);
    float pf = gst[erow * GP + 16 + ecol] + bf2f(z1);
    float pg = gst[erow * GP + 32 + ecol] + bf2f(z2);
    float po = gst[erow * GP + 48 + ecol] + bf2f(z3);
    float ig = fsig(pi), fg = fsig(pf), gg = ftanh(pg), og = fsig(po);
    float cn = fg * creg + ig * gg;
    creg = cn;
    float h = og * ftanh(cn);
    hnext[(size_t)brow * Hv + j] = f2bf(h);
    if (!last){
      dst_bf[((size_t)brow * Tv + t) * Hv + j] = f2bf(h);
    } else {
      out_h[((size_t)brow * Tv + t) * Hv + j] = h;
      out_c[((size_t)t * Bv + brow) * Hv + j] = cn;
    }

    // inter-block barrier (64 blocks sharing this mq).
    // __syncthreads drains each wave's stores (vmcnt) before the leader releases.
    __syncthreads();
    target += 64;
    if (tid == 0){
      __threadfence();   // release: write back L2 so remote XCDs can see h stores
      __hip_atomic_fetch_add(barp, 1u, __ATOMIC_RELAXED, __HIP_MEMORY_SCOPE_AGENT);
      if (!deadf){
        int guard = 0;
        while (__hip_atomic_load(barp, __ATOMIC_RELAXED, __HIP_MEMORY_SCOPE_AGENT) < target){
          __builtin_amdgcn_s_sleep(2);
          if (++guard > (1 << 20)) { deadf = 1; break; }   // failsafe: never hang
        }
      }
      __threadfence();   // acquire: invalidate caches so remote h writes are seen
    }
    __syncthreads();

    const u16* tp = hnext; hnext = (u16*)hprev; hprev = tp;
  }
}

// ---------------- host ----------------

extern "C" void kernel_launch(void* const* d_in, const int* in_sizes, int n_in,
                              void* d_out, int out_size, void* d_ws, size_t ws_size,
                              hipStream_t stream){
  const float* x = (const float*)d_in[0];
  const float *W[3][4], *U[3][4], *bb[3][4];
  for (int l = 0; l < 3; ++l)
    for (int g = 0; g < 4; ++g){
      W[l][g]  = (const float*)d_in[1 + l * 12 + g * 3 + 0];
      U[l][g]  = (const float*)d_in[1 + l * 12 + g * 3 + 1];
      bb[l][g] = (const float*)d_in[1 + l * 12 + g * 3 + 2];
    }

  char* ws = (char*)d_ws;
  u16* Zbf  = (u16*)ws;                                  // 256 MB
  u16* Xb0  = (u16*)(ws + 268435456ull);                 // 64 MB
  u16* Xb1  = (u16*)(ws + 335544320ull);                 // 64 MB
  u16* xbf  = (u16*)(ws + 402653184ull);                 // 32 MB
  u16* Wp[3] = { (u16*)(ws + 436207616ull),
                 (u16*)(ws + 440401920ull),
                 (u16*)(ws + 448790528ull) };
  u16* Up[3] = { (u16*)(ws + 457179136ull),
                 (u16*)(ws + 465567744ull),
                 (u16*)(ws + 473956352ull) };
  float* bias[3] = { (float*)(ws + 482344960ull),
                     (float*)(ws + 482361344ull),
                     (float*)(ws + 482377728ull) };
  unsigned* bar = (unsigned*)(ws + 482394112ull);        // barrier counters, 256B-padded
  u16* hA = (u16*)(ws + 482918400ull);                   // 256 KB
  u16* hB = (u16*)(ws + 483180544ull);                   // 256 KB

  float* out_h = (float*)d_out;
  float* out_c = out_h + (size_t)Bv * Tv * Hv;

  // x -> bf16 (32768 x 512)
  cvt_f32_bf16<<<dim3(16384), dim3(256), 0, stream>>>(x, xbf, (Bv * Tv * Dv) / 4);

  // pack weights (bf16, MFMA B-frag layout) + biases
  for (int l = 0; l < 3; ++l){
    int K = (l == 0) ? Dv : Hv;
    int KT = K >> 5;
    int ntshift = (K == Dv) ? 13 : 14;     // log2(KT*512)
    pack_b<<<dim3((NG * K) / 256), dim3(256), 0, stream>>>(
        W[l][0], W[l][1], W[l][2], W[l][3], Wp[l], KT - 1, ntshift);
    pack_b<<<dim3((NG * Hv) / 256), dim3(256), 0, stream>>>(
        U[l][0], U[l][1], U[l][2], U[l][3], Up[l], (Hv >> 5) - 1, 14);
    pack_bias<<<dim3(16), dim3(256), 0, stream>>>(
        bb[l][0], bb[l][1], bb[l][2], bb[l][3], bias[l]);
  }

  const u16* Ain[3] = { xbf, Xb0, Xb1 };
  const int  Kl[3]  = { Dv, Hv, Hv };

  for (int l = 0; l < 3; ++l){
    hipMemsetAsync(bar, 0, 4 * 64 * sizeof(unsigned), stream);
    hipMemsetAsync(hA, 0, (size_t)Bv * Hv * 2, stream);

    pregemm<<<dim3(64, 256), dim3(256), 0, stream>>>(Ain[l], Wp[l], bias[l], Zbf, Kl[l]);

    u16* dst_bf = (l == 0) ? Xb0 : (l == 1) ? Xb1 : nullptr;
    lstm_persist<<<dim3(64, 4), dim3(512), 0, stream>>>(
        Up[l], Zbf, hA, hB, dst_bf, out_h, out_c, bar, (l == 2) ? 1 : 0);
  }
}

// Round 3
// 18130.711 us; speedup vs baseline: 1.0450x; 1.0450x over previous
//
#include <hip/hip_runtime.h>

#define Bv 128
#define Tv 256
#define Dv 512
#define Hv 1024
#define NG 4096   // 4*H

typedef __bf16 bf16x8 __attribute__((ext_vector_type(8)));
typedef float  f32x4  __attribute__((ext_vector_type(4)));
typedef int    i32x4  __attribute__((ext_vector_type(4)));
typedef unsigned short u16;

__device__ __forceinline__ u16 f2bf(float f){
  unsigned u = __float_as_uint(f);
  u = (u + 0x7FFFu + ((u >> 16) & 1u)) >> 16;
  return (u16)u;
}
__device__ __forceinline__ float bf2f(u16 b){ return __uint_as_float(((unsigned)b) << 16); }
__device__ __forceinline__ float fsig(float x){ return 1.0f / (1.0f + __expf(-x)); }
__device__ __forceinline__ float ftanh(float x){ return 1.0f - 2.0f / (1.0f + __expf(2.0f * x)); }

// ---------------- setup kernels ----------------

__global__ void cvt_f32_bf16(const float* __restrict__ src, u16* __restrict__ dst, int n4){
  int i = blockIdx.x * 256 + threadIdx.x;
  if (i < n4){
    float4 v = ((const float4*)src)[i];
    ushort4 o;
    o.x = f2bf(v.x); o.y = f2bf(v.y); o.z = f2bf(v.z); o.w = f2bf(v.w);
    ((ushort4*)dst)[i] = o;
  }
}

// Pack 4 gate matrices [K, 1024] fp32 into MFMA B-frag layout:
// out index o = ((ntile*KT + ktile)*64 + lane)*8 + j
// element = W[gate][k*1024 + col], k = ktile*32 + (lane>>4)*8 + j,
// n = ntile*16 + (lane&15), gate = n>>10, col = n&1023.
__global__ void pack_b(const float* __restrict__ Wi, const float* __restrict__ Wf,
                       const float* __restrict__ Wg, const float* __restrict__ Wo,
                       u16* __restrict__ dst, int KTm1, int ntshift){
  int o = blockIdx.x * 256 + threadIdx.x;
  int j = o & 7;
  int lane = (o >> 3) & 63;
  int kt = (o >> 9) & KTm1;
  int ntile = o >> ntshift;
  int k = kt * 32 + ((lane >> 4) << 3) + j;
  int n = ntile * 16 + (lane & 15);
  const float* src = (n < 1024) ? Wi : (n < 2048) ? Wf : (n < 3072) ? Wg : Wo;
  dst[o] = f2bf(src[k * 1024 + (n & 1023)]);
}

__global__ void pack_bias(const float* __restrict__ bi, const float* __restrict__ bfp,
                          const float* __restrict__ bg, const float* __restrict__ bo,
                          float* __restrict__ dst){
  int n = blockIdx.x * 256 + threadIdx.x;   // 0..4095
  const float* s = (n < 1024) ? bi : (n < 2048) ? bfp : (n < 3072) ? bg : bo;
  dst[n] = s[n & 1023];
}

// ---------------- pre-GEMM: Z = A @ Wpacked + bias ----------------
__global__ __launch_bounds__(256) void pregemm(const u16* __restrict__ A,
                                               const u16* __restrict__ Wp,
                                               const float* __restrict__ bias,
                                               u16* __restrict__ Z,
                                               int K){
  int w = threadIdx.x >> 6, lane = threadIdx.x & 63;
  int quad = lane >> 4, l15 = lane & 15;
  int nblk = blockIdx.x;   // 0..63
  int mblk = blockIdx.y;   // 0..255
  int KT = K >> 5;
  const u16* Arow0 = A + (size_t)(mblk * 128 + w * 32 + l15) * K;
  const u16* Arow1 = Arow0 + (size_t)16 * K;
  f32x4 acc[2][4] = {};
  for (int kt = 0; kt < KT; ++kt){
    int kofs = kt * 32 + quad * 8;
    bf16x8 a0 = *(const bf16x8*)(Arow0 + kofs);
    bf16x8 a1 = *(const bf16x8*)(Arow1 + kofs);
#pragma unroll
    for (int g = 0; g < 4; ++g){
      int ntile = nblk * 4 + g;
      bf16x8 b = *(const bf16x8*)(Wp + ((size_t)(ntile * KT + kt) * 64 + lane) * 8);
      acc[0][g] = __builtin_amdgcn_mfma_f32_16x16x32_bf16(a0, b, acc[0][g], 0, 0, 0);
      acc[1][g] = __builtin_amdgcn_mfma_f32_16x16x32_bf16(a1, b, acc[1][g], 0, 0, 0);
    }
  }
#pragma unroll
  for (int mt = 0; mt < 2; ++mt){
    int rowbase = mblk * 128 + w * 32 + mt * 16 + quad * 4;
#pragma unroll
    for (int g = 0; g < 4; ++g){
      int n = (nblk * 4 + g) * 16 + l15;
      float bv = bias[n];
#pragma unroll
      for (int r = 0; r < 4; ++r){
        Z[(size_t)(rowbase + r) * NG + n] = f2bf(acc[mt][g][r] + bv);
      }
    }
  }
}

// ---------------- persistent recurrent kernel ----------------
// One launch per layer; loops all T=256 timesteps internally.
// grid = (64 jt, 4 mq): block owns batch rows [mq*32, mq*32+32) x h-cols [jt*16, jt*16+16).
// 8 waves = (mtile m = w&1, gate g = w>>1). Each wave holds its U B-frags in
// 128 VGPRs, PINNED via inline asm so the compiler cannot sink the loads back
// into the t-loop (round-2 counters: VGPR_Count=84 proved it rematerialized
// them, re-fetching U from L3 every step after the acquire fence's L2 inv).
// c state lives in one VGPR per thread.
// Steps separated by a per-mq-group (64 block) device barrier on bar[mq*64];
// h ping-pongs between hA/hB so a one-step skew between groups is safe.
// Residency: >128 VGPR -> exactly 8 waves/CU -> 1 block/CU -> all 256 blocks
// co-resident; barrier cannot deadlock by capacity. A bounded spin (sticky
// deadf) guarantees termination even if that assumption breaks.
#define GP 68   // gst row pitch (floats), padded to break bank conflicts

__global__ __launch_bounds__(512, 2) void lstm_persist(
    const u16* __restrict__ Up,
    const u16* __restrict__ Zbf,
    u16* hA, u16* hB,
    u16* __restrict__ dst_bf,
    float* __restrict__ out_h,
    float* __restrict__ out_c,
    unsigned* bar,
    int last)
{
  __shared__ float gst[32 * GP];   // gate pre-activations, 32 rows x 64 gate-cols
  int tid = threadIdx.x;
  int w = tid >> 6, lane = tid & 63;
  int quad = lane >> 4, l15 = lane & 15;
  int jt = blockIdx.x;      // 0..63  (h-col tile)
  int mq = blockIdx.y;      // 0..3   (batch group; barrier group)
  int m = w & 1, g = w >> 1;
  unsigned* barp = bar + mq * 64;   // 256B-padded counter per group

  // Load this wave's U fragments (gate g, ntile g*64+jt): 128 VGPRs, pinned.
  i32x4 bregi[32];
#pragma unroll
  for (int kt = 0; kt < 32; ++kt)
    bregi[kt] = *(const i32x4*)(Up + ((size_t)((g * 64 + jt) * 32 + kt) * 64 + lane) * 8);
#pragma unroll
  for (int kt = 0; kt < 32; ++kt)
    asm volatile("" : "+v"(bregi[kt]));   // forbid rematerialization; keep live in VGPRs

  // Elementwise ownership: thread -> (row erow, h-col ecol), fixed for all t.
  int erow = tid >> 4;          // 0..31
  int ecol = tid & 15;          // 0..15
  int brow = mq * 32 + erow;    // global batch row
  int j = jt * 16 + ecol;       // global h col
  float creg = 0.0f;            // cell state (fp32), persistent in register

  const u16* hprev = hA;
  u16* hnext = hB;
  unsigned target = 0;
  int deadf = 0;                // sticky spin-timeout flag (leader only)
  const int arowidx = mq * 32 + m * 16 + l15;
  const u16* zbase = Zbf + (size_t)brow * Tv * NG + j;

  // prefetch Z for t=0
  u16 z0 = zbase[0], z1 = zbase[Hv], z2 = zbase[2 * Hv], z3 = zbase[3 * Hv];

  for (int t = 0; t < Tv; ++t){
    // G_partial = hprev(mtile m) @ U(gate g, jt) -- same accumulation order as before
    const u16* arow = hprev + (size_t)arowidx * Hv + quad * 8;
    f32x4 acc = {};
#pragma unroll
    for (int kt = 0; kt < 32; ++kt){
      bf16x8 a = *(const bf16x8*)(arow + kt * 32);
      acc = __builtin_amdgcn_mfma_f32_16x16x32_bf16(
          a, __builtin_bit_cast(bf16x8, bregi[kt]), acc, 0, 0, 0);
    }
#pragma unroll
    for (int r = 0; r < 4; ++r)
      gst[(m * 16 + quad * 4 + r) * GP + g * 16 + l15] = acc[r];
    __syncthreads();

    // gates + state update (identical math to previous kernel)
    float pi = gst[erow * GP +  0 + ecol] + bf2f(z0);
    float pf = gst[erow * GP + 16 + ecol] + bf2f(z1);
    float pg = gst[erow * GP + 32 + ecol] + bf2f(z2);
    float po = gst[erow * GP + 48 + ecol] + bf2f(z3);
    float ig = fsig(pi), fg = fsig(pf), gg = ftanh(pg), og = fsig(po);
    float cn = fg * creg + ig * gg;
    creg = cn;
    float h = og * ftanh(cn);
    hnext[(size_t)brow * Hv + j] = f2bf(h);
    if (!last){
      dst_bf[((size_t)brow * Tv + t) * Hv + j] = f2bf(h);
    } else {
      out_h[((size_t)brow * Tv + t) * Hv + j] = h;
      out_c[((size_t)t * Bv + brow) * Hv + j] = cn;
    }

    // prefetch Z for t+1: issued now, lands during the barrier spin.
    if (t + 1 < Tv){
      const u16* zp = zbase + (size_t)(t + 1) * NG;
      z0 = zp[0]; z1 = zp[Hv]; z2 = zp[2 * Hv]; z3 = zp[3 * Hv];
    }

    // inter-block barrier (64 blocks sharing this mq).
    // __syncthreads drains each wave's stores (vmcnt) before the leader releases.
    __syncthreads();
    target += 64;
    if (tid == 0){
      // release arrive: flush this XCD's L2 so remote XCDs can see our h stores
      __hip_atomic_fetch_add(barp, 1u, __ATOMIC_RELEASE, __HIP_MEMORY_SCOPE_AGENT);
      if (!deadf){
        int guard = 0;
        while (__hip_atomic_load(barp, __ATOMIC_RELAXED, __HIP_MEMORY_SCOPE_AGENT) < target){
          __builtin_amdgcn_s_sleep(2);
          if (++guard > (1 << 20)) { deadf = 1; break; }   // failsafe: never hang
        }
      }
      __threadfence();   // acquire: invalidate caches so remote h writes are seen
    }
    __syncthreads();

    const u16* tp = hnext; hnext = (u16*)hprev; hprev = tp;
  }
}

// ---------------- host ----------------

extern "C" void kernel_launch(void* const* d_in, const int* in_sizes, int n_in,
                              void* d_out, int out_size, void* d_ws, size_t ws_size,
                              hipStream_t stream){
  const float* x = (const float*)d_in[0];
  const float *W[3][4], *U[3][4], *bb[3][4];
  for (int l = 0; l < 3; ++l)
    for (int g = 0; g < 4; ++g){
      W[l][g]  = (const float*)d_in[1 + l * 12 + g * 3 + 0];
      U[l][g]  = (const float*)d_in[1 + l * 12 + g * 3 + 1];
      bb[l][g] = (const float*)d_in[1 + l * 12 + g * 3 + 2];
    }

  char* ws = (char*)d_ws;
  u16* Zbf  = (u16*)ws;                                  // 256 MB
  u16* Xb0  = (u16*)(ws + 268435456ull);                 // 64 MB
  u16* Xb1  = (u16*)(ws + 335544320ull);                 // 64 MB
  u16* xbf  = (u16*)(ws + 402653184ull);                 // 32 MB
  u16* Wp[3] = { (u16*)(ws + 436207616ull),
                 (u16*)(ws + 440401920ull),
                 (u16*)(ws + 448790528ull) };
  u16* Up[3] = { (u16*)(ws + 457179136ull),
                 (u16*)(ws + 465567744ull),
                 (u16*)(ws + 473956352ull) };
  float* bias[3] = { (float*)(ws + 482344960ull),
                     (float*)(ws + 482361344ull),
                     (float*)(ws + 482377728ull) };
  unsigned* bar = (unsigned*)(ws + 482394112ull);        // barrier counters, 256B-padded
  u16* hA = (u16*)(ws + 482918400ull);                   // 256 KB
  u16* hB = (u16*)(ws + 483180544ull);                   // 256 KB

  float* out_h = (float*)d_out;
  float* out_c = out_h + (size_t)Bv * Tv * Hv;

  // x -> bf16 (32768 x 512)
  cvt_f32_bf16<<<dim3(16384), dim3(256), 0, stream>>>(x, xbf, (Bv * Tv * Dv) / 4);

  // pack weights (bf16, MFMA B-frag layout) + biases
  for (int l = 0; l < 3; ++l){
    int K = (l == 0) ? Dv : Hv;
    int KT = K >> 5;
    int ntshift = (K == Dv) ? 13 : 14;     // log2(KT*512)
    pack_b<<<dim3((NG * K) / 256), dim3(256), 0, stream>>>(
        W[l][0], W[l][1], W[l][2], W[l][3], Wp[l], KT - 1, ntshift);
    pack_b<<<dim3((NG * Hv) / 256), dim3(256), 0, stream>>>(
        U[l][0], U[l][1], U[l][2], U[l][3], Up[l], (Hv >> 5) - 1, 14);
    pack_bias<<<dim3(16), dim3(256), 0, stream>>>(
        bb[l][0], bb[l][1], bb[l][2], bb[l][3], bias[l]);
  }

  const u16* Ain[3] = { xbf, Xb0, Xb1 };
  const int  Kl[3]  = { Dv, Hv, Hv };

  for (int l = 0; l < 3; ++l){
    hipMemsetAsync(bar, 0, 4 * 64 * sizeof(unsigned), stream);
    hipMemsetAsync(hA, 0, (size_t)Bv * Hv * 2, stream);

    pregemm<<<dim3(64, 256), dim3(256), 0, stream>>>(Ain[l], Wp[l], bias[l], Zbf, Kl[l]);

    u16* dst_bf = (l == 0) ? Xb0 : (l == 1) ? Xb1 : nullptr;
    lstm_persist<<<dim3(64, 4), dim3(512), 0, stream>>>(
        Up[l], Zbf, hA, hB, dst_bf, out_h, out_c, bar, (l == 2) ? 1 : 0);
  }
}